// Round 17
// baseline (21.989 us; speedup 1.0000x reference)
//
#include <hip/hip_runtime.h>

#define V 64
#define W 5
#define G 80
#define O 80
#define NROT 16
#define GPAD 104          // elems per descT row (208 B: 16B-aligned, 2-way banks)
#define EPSV 1e-5f
#define NLOG2E (-1.4426950408889634f)

#define TSTR 72           // elems per s_A row (144 B)
#define XSTR 68           // f32 per row of s_x/s_arg/s_fT (272 B)

using f32x4 = __attribute__((ext_vector_type(4))) float;

__device__ __forceinline__ unsigned short f2bf(float x) {
    unsigned u = __float_as_uint(x);
    unsigned r = (u + 0x7FFFu + ((u >> 16) & 1u)) >> 16;   // RNE
    return (unsigned short)r;
}
__device__ __forceinline__ float pick5(float a0, float a1, float a2,
                                       float a3, float a4, int r) {
    float x = (r == 1) ? a1 : a0;
    x = (r == 2) ? a2 : x;
    x = (r == 3) ? a3 : x;
    x = (r == 4) ? a4 : x;
    return x;
}

// ---- MFMA element type: f16 if available, else bf16 (both validated) ----
#if __has_builtin(__builtin_amdgcn_mfma_f32_16x16x32_f16)
typedef _Float16 elem_t;
typedef elem_t efrag __attribute__((ext_vector_type(8)));
#define EMFMA(a, b, c) __builtin_amdgcn_mfma_f32_16x16x32_f16((a), (b), (c), 0, 0, 0)
__device__ __forceinline__ unsigned epack(float a, float b) {
    auto r = __builtin_amdgcn_cvt_pkrtz(a, b);
    return __builtin_bit_cast(unsigned, r);
}
__device__ __forceinline__ unsigned short estore(float x) {
    return __builtin_bit_cast(unsigned short, (_Float16)x);   // 1 instr
}
#else
typedef short elem_t;
typedef elem_t efrag __attribute__((ext_vector_type(8)));
#define EMFMA(a, b, c) __builtin_amdgcn_mfma_f32_16x16x32_bf16((a), (b), (c), 0, 0, 0)
__device__ __forceinline__ unsigned epack(float a, float b) {
    return (unsigned)f2bf(a) | ((unsigned)f2bf(b) << 16);
}
__device__ __forceinline__ unsigned short estore(float x) { return f2bf(x); }
#endif

// ============================================================================
// SINGLE fused kernel: one block per point, 320 threads = 5 waves, 3 barriers.
// Stage 2: C[32x256] = F''[32x64] x T[64x256]; A staged in LDS, T in-register.
// Stage 3: Wc B-frags loaded from global INSIDE the nt-loop.
// (320,6): VGPR cap ~84 -> 24 waves/CU -> 4 blocks/CU (+33% concurrency).
// ============================================================================
__global__ __launch_bounds__(320, 6) void conv_kernel(
    const float* __restrict__ feat,      // [NP][V][W]
    const float* __restrict__ rho,       // [NP][V]
    const float* __restrict__ theta,     // [NP][V]
    const float* __restrict__ mask,      // [NP][V]
    const float* __restrict__ mu_rho,    // [W][G]
    const float* __restrict__ mu_theta,  // [W][G]
    const float* __restrict__ sig_rho,   // [W][G]
    const float* __restrict__ sig_theta, // [W][G]
    const float* __restrict__ Wc,        // [W][G][O]
    const float* __restrict__ bc,        // [W][O]
    float* __restrict__ out)             // [NP][W][O]
{
    __shared__ __align__(16) float s_x[NROT][XSTR];            // 4352 B
    __shared__ __align__(16) float s_fT[W][XSTR];              // 1360 B
    __shared__ __align__(16) float s_arg[5][XSTR];             // 1360 B
    __shared__ __align__(16) elem_t s_A[32 * TSTR];            // 4608 B
    __shared__ __align__(16) elem_t s_descT[W * NROT * GPAD];  // 16640 B
    __shared__ float s_ct[16], s_mt[16], s_sre[8];

    const int tid = threadIdx.x;
    const int p = blockIdx.x;
    const int g = tid % G;   // 0..79
    const int j = tid / G;   // 0..3

    const float kstep = 0.39269908169872414f;      // 2*pi/16
    const float two_pi = 6.283185307179586f;
    const float inv_two_pi = 0.15915494309189535f;

    // ---- phase 1: stage all point data (no internal deps) ----
    {
        int v = tid / 5, w = tid - 5 * (tid / 5);
        s_fT[w][v] = feat[p * V * W + tid];        // tid == v*5+w
    }
    {
        int r = tid >> 6, v = tid & 63;
        float mu_r = mu_rho[r * 16];
        float sr   = sig_rho[r * 16];
        float c_r  = NLOG2E / (sr * sr + EPSV);
        float rv   = rho[p * V + v];
        float mk   = (mask[p * V + v] != 0.0f) ? 0.0f : -1e30f;
        float dr = rv - mu_r;
        s_arg[r][v] = fmaf(dr * dr, c_r, mk);      // mask folded
    }
    if (tid < 16) {
        float st = sig_theta[tid];
        s_ct[tid] = NLOG2E / (st * st + EPSV);
        s_mt[tid] = mu_theta[tid];
    }
    for (int i = tid; i < V * NROT; i += 320) {
        int v = i >> 4, k = i & 15;
        float x = theta[p * V + v] + (float)k * kstep;
        x -= floorf(x * inv_two_pi) * two_pi;      // jnp.mod(x, 2pi)
        s_x[k][v] = x;
    }
    // descT g-pad zero (elems 80..103 = u32 cols 40..51) — off critical path
    {
        unsigned* d32 = (unsigned*)s_descT;
        for (int i = tid; i < 80 * 12; i += 320)
            d32[(i / 12) * (GPAD / 2) + 40 + (i % 12)] = 0u;
    }

    // uniformity + meshgrid check
    const int wchk = 1 + j;
    const int gr = (g >> 4) << 4;
    const int gt = g & 15;
    int pred = (mu_rho  [wchk * G + g] == mu_rho  [g]) &&
               (mu_theta[wchk * G + g] == mu_theta[g]) &&
               (sig_rho [wchk * G + g] == sig_rho [g]) &&
               (sig_theta[wchk * G + g] == sig_theta[g]) &&
               (mu_rho  [g] == mu_rho  [gr]) &&
               (sig_rho [g] == sig_rho [gr]) &&
               (mu_theta[g] == mu_theta[gt]) &&
               (sig_theta[g] == sig_theta[gt]);
    const int uni = __syncthreads_and(pred);       // barrier #1

    if (uni) {
        // ---- phase 2: F'' build (tid<256) || sre (tid 256..260) ----
        if (tid < 256) {
            int m = tid >> 3, s = tid & 7;
            unsigned pk0 = 0, pk1 = 0, pk2 = 0, pk3 = 0;
            if (m < 30) {
                int w  = m / 5;
                int rr = (m < 25) ? (m - 5 * w) : (m - 25);
                float mx = -3.0e38f;               // inline per-row shift scan
                #pragma unroll
                for (int vs = 0; vs < 16; ++vs) {
                    float4 a = *(const float4*)&s_arg[rr][4 * vs];
                    mx = fmaxf(mx, fmaxf(fmaxf(a.x, a.y), fmaxf(a.z, a.w)));
                }
                float sh = fminf(-mx, 60.0f);
                const float* ap = &s_arg[rr][8 * s];
                float4 aa = *(const float4*)ap;
                float4 ab = *(const float4*)(ap + 4);
                float e0 = __builtin_amdgcn_exp2f(aa.x + sh);
                float e1 = __builtin_amdgcn_exp2f(aa.y + sh);
                float e2 = __builtin_amdgcn_exp2f(aa.z + sh);
                float e3 = __builtin_amdgcn_exp2f(aa.w + sh);
                float e4 = __builtin_amdgcn_exp2f(ab.x + sh);
                float e5 = __builtin_amdgcn_exp2f(ab.y + sh);
                float e6 = __builtin_amdgcn_exp2f(ab.z + sh);
                float e7 = __builtin_amdgcn_exp2f(ab.w + sh);
                if (m < 25) {
                    const float* fp = &s_fT[w][8 * s];
                    float4 fa = *(const float4*)fp;
                    float4 fb = *(const float4*)(fp + 4);
                    e0 *= fa.x; e1 *= fa.y; e2 *= fa.z; e3 *= fa.w;
                    e4 *= fb.x; e5 *= fb.y; e6 *= fb.z; e7 *= fb.w;
                }
                pk0 = epack(e0, e1); pk1 = epack(e2, e3);
                pk2 = epack(e4, e5); pk3 = epack(e6, e7);
            }
            *(uint4*)(s_A + m * TSTR + 8 * s) = make_uint4(pk0, pk1, pk2, pk3);
        } else if (tid < 261) {
            int r = tid - 256;
            float mx = -3.0e38f;
            #pragma unroll
            for (int vs = 0; vs < 16; ++vs) {
                float4 a = *(const float4*)&s_arg[r][4 * vs];
                mx = fmaxf(mx, fmaxf(fmaxf(a.x, a.y), fmaxf(a.z, a.w)));
            }
            float sh = fminf(-mx, 60.0f);
            s_sre[r] = EPSV * __builtin_amdgcn_exp2f(sh);
        }
        __syncthreads();                           // barrier #2 (A ready)

        // ---- phase 3: MFMA + in-register T + shfl-den + normalize ----
        const int ww = tid >> 6;     // wave 0..4
        const int l  = tid & 63;
        const int lg = l >> 4, lc = l & 15;
        efrag a00 = *(const efrag*)(s_A + lc * TSTR + (lg << 3));
        efrag a01 = *(const efrag*)(s_A + lc * TSTR + 32 + (lg << 3));
        efrag a10 = *(const efrag*)(s_A + (16 + lc) * TSTR + (lg << 3));
        efrag a11 = *(const efrag*)(s_A + (16 + lc) * TSTR + 32 + (lg << 3));
        const float sre0 = s_sre[0], sre1 = s_sre[1], sre2 = s_sre[2],
                    sre3 = s_sre[3], sre4 = s_sre[4];

        int w0[4], r0[4], w1[4], r1[4];
        bool ok1[4];
        #pragma unroll
        for (int i = 0; i < 4; ++i) {
            int m = lg * 4 + i;
            w0[i] = m / 5; r0[i] = m - 5 * w0[i];
            int m2 = 16 + lg * 4 + i;
            ok1[i] = (m2 < 25);
            int mm = ok1[i] ? m2 : 24;
            w1[i] = mm / 5; r1[i] = mm - 5 * w1[i];
        }

        #pragma unroll
        for (int q = 0; q < 4; ++q) {
            int nt = ww + 5 * q;                   // wave-uniform
            if (nt < 16) {
                float ct = s_ct[nt], mt = s_mt[nt];
                const float* xr = &s_x[lc][lg << 3];
                float4 xa = *(const float4*)(xr);
                float4 xb = *(const float4*)(xr + 4);
                float4 xc = *(const float4*)(xr + 32);
                float4 xd = *(const float4*)(xr + 36);
                float d;
                #define EX(v) (d = (v) - mt, __builtin_amdgcn_exp2f(ct * d * d))
                unsigned u0 = epack(EX(xa.x), EX(xa.y));
                unsigned u1 = epack(EX(xa.z), EX(xa.w));
                unsigned u2 = epack(EX(xb.x), EX(xb.y));
                unsigned u3 = epack(EX(xb.z), EX(xb.w));
                efrag b0 = __builtin_bit_cast(efrag, make_uint4(u0, u1, u2, u3));
                u0 = epack(EX(xc.x), EX(xc.y));
                u1 = epack(EX(xc.z), EX(xc.w));
                u2 = epack(EX(xd.x), EX(xd.y));
                u3 = epack(EX(xd.z), EX(xd.w));
                efrag b1 = __builtin_bit_cast(efrag, make_uint4(u0, u1, u2, u3));
                #undef EX

                f32x4 z = {0.f, 0.f, 0.f, 0.f};
                __builtin_amdgcn_s_setprio(1);
                f32x4 c0 = EMFMA(a00, b0, z);
                c0 = EMFMA(a01, b1, c0);
                f32x4 c1 = EMFMA(a10, b0, z);
                c1 = EMFMA(a11, b1, c1);
                __builtin_amdgcn_s_setprio(0);

                // dens (F'' rows 25..29) live in lanes 32+lc / 48+lc
                float dn0 = __shfl(c1[1], 32 + lc);
                float dn1 = __shfl(c1[2], 32 + lc);
                float dn2 = __shfl(c1[3], 32 + lc);
                float dn3 = __shfl(c1[0], 48 + lc);
                float dn4 = __shfl(c1[1], 48 + lc);
                float i0 = __builtin_amdgcn_rcpf(dn0 + sre0);
                float i1 = __builtin_amdgcn_rcpf(dn1 + sre1);
                float i2 = __builtin_amdgcn_rcpf(dn2 + sre2);
                float i3 = __builtin_amdgcn_rcpf(dn3 + sre3);
                float i4 = __builtin_amdgcn_rcpf(dn4 + sre4);

                #pragma unroll
                for (int i = 0; i < 4; ++i) {
                    float inv = pick5(i0, i1, i2, i3, i4, r0[i]);
                    s_descT[(w0[i] * 16 + lc) * GPAD + r0[i] * 16 + nt] =
                        (elem_t)__builtin_bit_cast(elem_t, estore(c0[i] * inv));
                }
                #pragma unroll
                for (int i = 0; i < 4; ++i) {
                    if (ok1[i]) {
                        float inv = pick5(i0, i1, i2, i3, i4, r1[i]);
                        s_descT[(w1[i] * 16 + lc) * GPAD + r1[i] * 16 + nt] =
                            (elem_t)__builtin_bit_cast(elem_t, estore(c1[i] * inv));
                    }
                }
            }
        }
    } else {
        // ---- generic fallback: per-w gaussians (correctness path) ----
        #pragma unroll 1
        for (int w = 0; w < W; ++w) {
            const float mu_r = mu_rho[w * G + g];
            const float sr   = sig_rho[w * G + g];
            const float c_sr = NLOG2E / (sr * sr + EPSV);
            const float mu_t = mu_theta[w * G + g];
            const float st   = sig_theta[w * G + g];
            const float c_st = NLOG2E / (st * st + EPSV);
            float den[4] = {0.f, 0.f, 0.f, 0.f};
            float nm[4]  = {0.f, 0.f, 0.f, 0.f};
            for (int v = 0; v < V; ++v) {
                float rv  = rho[p * V + v];
                float mk  = (mask[p * V + v] != 0.0f) ? 0.0f : -1e30f;
                float fw  = s_fT[w][v];
                float dr = rv - mu_r;
                float argr = fmaf(dr * dr, c_sr, mk);
                #pragma unroll
                for (int kk = 0; kk < 4; ++kk) {
                    float x = s_x[4 * j + kk][v];
                    float t = x - mu_t;
                    float e = __builtin_amdgcn_exp2f(fmaf(t * t, c_st, argr));
                    den[kk] += e;
                    nm[kk] = fmaf(e, fw, nm[kk]);
                }
            }
            #pragma unroll
            for (int kk = 0; kk < 4; ++kk)
                s_descT[(w * 16 + 4 * j + kk) * GPAD + g] =
                    (elem_t)__builtin_bit_cast(elem_t,
                        estore(nm[kk] * __builtin_amdgcn_rcpf(den[kk] + EPSV)));
        }
    }

    __syncthreads();                               // barrier #3 (descT ready)

    // ---- stage-3 MFMA: out = max_k descT x Wc + bc; Wc loaded per-nt ----
    {
        const int ww = tid >> 6;
        const int l  = tid & 63;
        const int lg = l >> 4, lc = l & 15;
        efrag afrag[3];
        #pragma unroll
        for (int ks = 0; ks < 3; ++ks)
            afrag[ks] = *(const efrag*)(s_descT + (ww * 16 + lc) * GPAD +
                                        ks * 32 + (lg << 3));
        // lane's Wc column base: row g stride O floats
        const float* wbase = Wc + (size_t)(ww * G) * O + lc;

        #pragma unroll 1
        for (int nt = 0; nt < 5; ++nt) {
            const float* wp = wbase + nt * 16;
            // load 3 B-frags (24 floats, bounded live range, no barrier cross)
            float v0[8], v1[8], v2[8];
            #pragma unroll
            for (int i = 0; i < 8; ++i) {
                int ga = (lg << 3) + i;            // ks=0: g 0..31
                int gb = 32 + (lg << 3) + i;       // ks=1: g 32..63
                int gc = 64 + (lg << 3) + i;       // ks=2: g 64..95 (pad>=80)
                v0[i] = wp[(size_t)ga * O];
                v1[i] = wp[(size_t)gb * O];
                v2[i] = (gc < G) ? wp[(size_t)gc * O] : 0.0f;
            }
            efrag b0 = __builtin_bit_cast(efrag, make_uint4(
                epack(v0[0], v0[1]), epack(v0[2], v0[3]),
                epack(v0[4], v0[5]), epack(v0[6], v0[7])));
            efrag b1 = __builtin_bit_cast(efrag, make_uint4(
                epack(v1[0], v1[1]), epack(v1[2], v1[3]),
                epack(v1[4], v1[5]), epack(v1[6], v1[7])));
            efrag b2 = __builtin_bit_cast(efrag, make_uint4(
                epack(v2[0], v2[1]), epack(v2[2], v2[3]),
                epack(v2[4], v2[5]), epack(v2[6], v2[7])));

            f32x4 acc = {0.f, 0.f, 0.f, 0.f};
            __builtin_amdgcn_s_setprio(1);
            acc = EMFMA(afrag[0], b0, acc);
            acc = EMFMA(afrag[1], b1, acc);
            acc = EMFMA(afrag[2], b2, acc);
            __builtin_amdgcn_s_setprio(0);
            float m1 = fmaxf(fmaxf(acc[0], acc[1]), fmaxf(acc[2], acc[3]));
            m1 = fmaxf(m1, __shfl_xor(m1, 16));
            m1 = fmaxf(m1, __shfl_xor(m1, 32));
            if (l < 16) {
                int oo = nt * 16 + l;
                out[p * (W * O) + ww * O + oo] = m1 + bc[ww * O + oo];
            }
        }
    }
}

extern "C" void kernel_launch(void* const* d_in, const int* in_sizes, int n_in,
                              void* d_out, int out_size, void* d_ws, size_t ws_size,
                              hipStream_t stream) {
    const float* feat      = (const float*)d_in[0];
    const float* rho       = (const float*)d_in[1];
    const float* theta     = (const float*)d_in[2];
    const float* mask      = (const float*)d_in[3];
    const float* mu_rho    = (const float*)d_in[4];
    const float* mu_theta  = (const float*)d_in[5];
    const float* sig_rho   = (const float*)d_in[6];
    const float* sig_theta = (const float*)d_in[7];
    const float* Wc        = (const float*)d_in[8];
    const float* bc        = (const float*)d_in[9];
    float* outp            = (float*)d_out;

    const int np = in_sizes[1] / V;   // B*N points
    conv_kernel<<<np, 320, 0, stream>>>(feat, rho, theta, mask, mu_rho, mu_theta,
                                        sig_rho, sig_theta, Wc, bc, outp);
}

// Round 18
// 21.399 us; speedup vs baseline: 1.0276x; 1.0276x over previous
//
#include <hip/hip_runtime.h>

#define V 64
#define W 5
#define G 80
#define O 80
#define NROT 16
#define GPAD 104          // elems per descT row (208 B: 16B-aligned, 2-way banks)
#define EPSV 1e-5f
#define NLOG2E (-1.4426950408889634f)

#define TSTR 72           // elems per s_A row (144 B)
#define XSTR 68           // f32 per row of s_x/s_arg/s_fT (272 B)

using f32x4 = __attribute__((ext_vector_type(4))) float;

__device__ __forceinline__ unsigned short f2bf(float x) {
    unsigned u = __float_as_uint(x);
    unsigned r = (u + 0x7FFFu + ((u >> 16) & 1u)) >> 16;   // RNE
    return (unsigned short)r;
}
__device__ __forceinline__ float pick5(float a0, float a1, float a2,
                                       float a3, float a4, int r) {
    float x = (r == 1) ? a1 : a0;
    x = (r == 2) ? a2 : x;
    x = (r == 3) ? a3 : x;
    x = (r == 4) ? a4 : x;
    return x;
}

// ---- MFMA element type: f16 if available, else bf16 (both validated) ----
#if __has_builtin(__builtin_amdgcn_mfma_f32_16x16x32_f16)
typedef _Float16 elem_t;
typedef elem_t efrag __attribute__((ext_vector_type(8)));
#define EMFMA(a, b, c) __builtin_amdgcn_mfma_f32_16x16x32_f16((a), (b), (c), 0, 0, 0)
__device__ __forceinline__ unsigned epack(float a, float b) {
    auto r = __builtin_amdgcn_cvt_pkrtz(a, b);
    return __builtin_bit_cast(unsigned, r);
}
__device__ __forceinline__ unsigned short estore(float x) {
    return __builtin_bit_cast(unsigned short, (_Float16)x);   // 1 instr
}
#else
typedef short elem_t;
typedef elem_t efrag __attribute__((ext_vector_type(8)));
#define EMFMA(a, b, c) __builtin_amdgcn_mfma_f32_16x16x32_bf16((a), (b), (c), 0, 0, 0)
__device__ __forceinline__ unsigned epack(float a, float b) {
    return (unsigned)f2bf(a) | ((unsigned)f2bf(b) << 16);
}
__device__ __forceinline__ unsigned short estore(float x) { return f2bf(x); }
#endif

// ============================================================================
// SINGLE fused kernel: one block per point, 320 threads = 5 waves, 3 barriers.
// Stage 2: C[32x256] = F''[32x64] x T[64x256]; A staged in LDS, T in-register.
// Stage 3: Wc B-frags loaded from global INSIDE the nt-loop.
// Delta vs 21.8us best: per-row shift computed by phase-1 wave shfl-reduce
// (wave r owns arg-row r in registers) -> phase-2 drops 16 b128 LDS reads
// + 64 fmax per thread.
// ============================================================================
__global__ __launch_bounds__(320, 5) void conv_kernel(
    const float* __restrict__ feat,      // [NP][V][W]
    const float* __restrict__ rho,       // [NP][V]
    const float* __restrict__ theta,     // [NP][V]
    const float* __restrict__ mask,      // [NP][V]
    const float* __restrict__ mu_rho,    // [W][G]
    const float* __restrict__ mu_theta,  // [W][G]
    const float* __restrict__ sig_rho,   // [W][G]
    const float* __restrict__ sig_theta, // [W][G]
    const float* __restrict__ Wc,        // [W][G][O]
    const float* __restrict__ bc,        // [W][O]
    float* __restrict__ out)             // [NP][W][O]
{
    __shared__ __align__(16) float s_x[NROT][XSTR];            // 4352 B
    __shared__ __align__(16) float s_fT[W][XSTR];              // 1360 B
    __shared__ __align__(16) float s_arg[5][XSTR];             // 1360 B
    __shared__ __align__(16) elem_t s_A[32 * TSTR];            // 4608 B
    __shared__ __align__(16) elem_t s_descT[W * NROT * GPAD];  // 16640 B
    __shared__ float s_ct[16], s_mt[16], s_shift[8], s_sre[8];

    const int tid = threadIdx.x;
    const int p = blockIdx.x;
    const int g = tid % G;   // 0..79
    const int j = tid / G;   // 0..3

    const float kstep = 0.39269908169872414f;      // 2*pi/16
    const float two_pi = 6.283185307179586f;
    const float inv_two_pi = 0.15915494309189535f;

    // ---- phase 1: stage all point data + wave shift-reduce ----
    {
        int v = tid / 5, w = tid - 5 * (tid / 5);
        s_fT[w][v] = feat[p * V * W + tid];        // tid == v*5+w
    }
    {
        int r = tid >> 6, v = tid & 63;            // wave r owns arg-row r
        float mu_r = mu_rho[r * 16];
        float sr   = sig_rho[r * 16];
        float c_r  = NLOG2E / (sr * sr + EPSV);
        float rv   = rho[p * V + v];
        float mk   = (mask[p * V + v] != 0.0f) ? 0.0f : -1e30f;
        float dr = rv - mu_r;
        float av = fmaf(dr * dr, c_r, mk);         // mask folded
        s_arg[r][v] = av;
        float m = av;                              // in-wave max reduce
        m = fmaxf(m, __shfl_xor(m, 1));
        m = fmaxf(m, __shfl_xor(m, 2));
        m = fmaxf(m, __shfl_xor(m, 4));
        m = fmaxf(m, __shfl_xor(m, 8));
        m = fmaxf(m, __shfl_xor(m, 16));
        m = fmaxf(m, __shfl_xor(m, 32));
        if (v == 0) {
            float sh = fminf(-m, 60.0f);           // arg <= 0 -> sh >= 0
            s_shift[r] = sh;
            s_sre[r]   = EPSV * __builtin_amdgcn_exp2f(sh);
        }
    }
    if (tid < 16) {
        float st = sig_theta[tid];
        s_ct[tid] = NLOG2E / (st * st + EPSV);
        s_mt[tid] = mu_theta[tid];
    }
    for (int i = tid; i < V * NROT; i += 320) {
        int v = i >> 4, k = i & 15;
        float x = theta[p * V + v] + (float)k * kstep;
        x -= floorf(x * inv_two_pi) * two_pi;      // jnp.mod(x, 2pi)
        s_x[k][v] = x;
    }
    // descT g-pad zero (elems 80..103 = u32 cols 40..51) — off critical path
    {
        unsigned* d32 = (unsigned*)s_descT;
        for (int i = tid; i < 80 * 12; i += 320)
            d32[(i / 12) * (GPAD / 2) + 40 + (i % 12)] = 0u;
    }

    // uniformity + meshgrid check
    const int wchk = 1 + j;
    const int gr = (g >> 4) << 4;
    const int gt = g & 15;
    int pred = (mu_rho  [wchk * G + g] == mu_rho  [g]) &&
               (mu_theta[wchk * G + g] == mu_theta[g]) &&
               (sig_rho [wchk * G + g] == sig_rho [g]) &&
               (sig_theta[wchk * G + g] == sig_theta[g]) &&
               (mu_rho  [g] == mu_rho  [gr]) &&
               (sig_rho [g] == sig_rho [gr]) &&
               (mu_theta[g] == mu_theta[gt]) &&
               (sig_theta[g] == sig_theta[gt]);
    const int uni = __syncthreads_and(pred);       // barrier #1

    if (uni) {
        // ---- phase 2: F'' build (tid<256) using precomputed s_shift ----
        if (tid < 256) {
            int m = tid >> 3, s = tid & 7;
            unsigned pk0 = 0, pk1 = 0, pk2 = 0, pk3 = 0;
            if (m < 30) {
                int w  = m / 5;
                int rr = (m < 25) ? (m - 5 * w) : (m - 25);
                float sh = s_shift[rr];
                const float* ap = &s_arg[rr][8 * s];
                float4 aa = *(const float4*)ap;
                float4 ab = *(const float4*)(ap + 4);
                float e0 = __builtin_amdgcn_exp2f(aa.x + sh);
                float e1 = __builtin_amdgcn_exp2f(aa.y + sh);
                float e2 = __builtin_amdgcn_exp2f(aa.z + sh);
                float e3 = __builtin_amdgcn_exp2f(aa.w + sh);
                float e4 = __builtin_amdgcn_exp2f(ab.x + sh);
                float e5 = __builtin_amdgcn_exp2f(ab.y + sh);
                float e6 = __builtin_amdgcn_exp2f(ab.z + sh);
                float e7 = __builtin_amdgcn_exp2f(ab.w + sh);
                if (m < 25) {
                    const float* fp = &s_fT[w][8 * s];
                    float4 fa = *(const float4*)fp;
                    float4 fb = *(const float4*)(fp + 4);
                    e0 *= fa.x; e1 *= fa.y; e2 *= fa.z; e3 *= fa.w;
                    e4 *= fb.x; e5 *= fb.y; e6 *= fb.z; e7 *= fb.w;
                }
                pk0 = epack(e0, e1); pk1 = epack(e2, e3);
                pk2 = epack(e4, e5); pk3 = epack(e6, e7);
            }
            *(uint4*)(s_A + m * TSTR + 8 * s) = make_uint4(pk0, pk1, pk2, pk3);
        }
        __syncthreads();                           // barrier #2 (A ready)

        // ---- phase 3: MFMA + in-register T + shfl-den + normalize ----
        const int ww = tid >> 6;     // wave 0..4
        const int l  = tid & 63;
        const int lg = l >> 4, lc = l & 15;
        efrag a00 = *(const efrag*)(s_A + lc * TSTR + (lg << 3));
        efrag a01 = *(const efrag*)(s_A + lc * TSTR + 32 + (lg << 3));
        efrag a10 = *(const efrag*)(s_A + (16 + lc) * TSTR + (lg << 3));
        efrag a11 = *(const efrag*)(s_A + (16 + lc) * TSTR + 32 + (lg << 3));
        const float sre0 = s_sre[0], sre1 = s_sre[1], sre2 = s_sre[2],
                    sre3 = s_sre[3], sre4 = s_sre[4];

        int w0[4], r0[4], w1[4], r1[4];
        bool ok1[4];
        #pragma unroll
        for (int i = 0; i < 4; ++i) {
            int m = lg * 4 + i;
            w0[i] = m / 5; r0[i] = m - 5 * w0[i];
            int m2 = 16 + lg * 4 + i;
            ok1[i] = (m2 < 25);
            int mm = ok1[i] ? m2 : 24;
            w1[i] = mm / 5; r1[i] = mm - 5 * w1[i];
        }

        #pragma unroll
        for (int q = 0; q < 4; ++q) {
            int nt = ww + 5 * q;                   // wave-uniform
            if (nt < 16) {
                float ct = s_ct[nt], mt = s_mt[nt];
                const float* xr = &s_x[lc][lg << 3];
                float4 xa = *(const float4*)(xr);
                float4 xb = *(const float4*)(xr + 4);
                float4 xc = *(const float4*)(xr + 32);
                float4 xd = *(const float4*)(xr + 36);
                float d;
                #define EX(v) (d = (v) - mt, __builtin_amdgcn_exp2f(ct * d * d))
                unsigned u0 = epack(EX(xa.x), EX(xa.y));
                unsigned u1 = epack(EX(xa.z), EX(xa.w));
                unsigned u2 = epack(EX(xb.x), EX(xb.y));
                unsigned u3 = epack(EX(xb.z), EX(xb.w));
                efrag b0 = __builtin_bit_cast(efrag, make_uint4(u0, u1, u2, u3));
                u0 = epack(EX(xc.x), EX(xc.y));
                u1 = epack(EX(xc.z), EX(xc.w));
                u2 = epack(EX(xd.x), EX(xd.y));
                u3 = epack(EX(xd.z), EX(xd.w));
                efrag b1 = __builtin_bit_cast(efrag, make_uint4(u0, u1, u2, u3));
                #undef EX

                f32x4 z = {0.f, 0.f, 0.f, 0.f};
                __builtin_amdgcn_s_setprio(1);
                f32x4 c0 = EMFMA(a00, b0, z);
                c0 = EMFMA(a01, b1, c0);
                f32x4 c1 = EMFMA(a10, b0, z);
                c1 = EMFMA(a11, b1, c1);
                __builtin_amdgcn_s_setprio(0);

                // dens (F'' rows 25..29) live in lanes 32+lc / 48+lc
                float dn0 = __shfl(c1[1], 32 + lc);
                float dn1 = __shfl(c1[2], 32 + lc);
                float dn2 = __shfl(c1[3], 32 + lc);
                float dn3 = __shfl(c1[0], 48 + lc);
                float dn4 = __shfl(c1[1], 48 + lc);
                float i0 = __builtin_amdgcn_rcpf(dn0 + sre0);
                float i1 = __builtin_amdgcn_rcpf(dn1 + sre1);
                float i2 = __builtin_amdgcn_rcpf(dn2 + sre2);
                float i3 = __builtin_amdgcn_rcpf(dn3 + sre3);
                float i4 = __builtin_amdgcn_rcpf(dn4 + sre4);

                #pragma unroll
                for (int i = 0; i < 4; ++i) {
                    float inv = pick5(i0, i1, i2, i3, i4, r0[i]);
                    s_descT[(w0[i] * 16 + lc) * GPAD + r0[i] * 16 + nt] =
                        (elem_t)__builtin_bit_cast(elem_t, estore(c0[i] * inv));
                }
                #pragma unroll
                for (int i = 0; i < 4; ++i) {
                    if (ok1[i]) {
                        float inv = pick5(i0, i1, i2, i3, i4, r1[i]);
                        s_descT[(w1[i] * 16 + lc) * GPAD + r1[i] * 16 + nt] =
                            (elem_t)__builtin_bit_cast(elem_t, estore(c1[i] * inv));
                    }
                }
            }
        }
    } else {
        // ---- generic fallback: per-w gaussians (correctness path) ----
        #pragma unroll 1
        for (int w = 0; w < W; ++w) {
            const float mu_r = mu_rho[w * G + g];
            const float sr   = sig_rho[w * G + g];
            const float c_sr = NLOG2E / (sr * sr + EPSV);
            const float mu_t = mu_theta[w * G + g];
            const float st   = sig_theta[w * G + g];
            const float c_st = NLOG2E / (st * st + EPSV);
            float den[4] = {0.f, 0.f, 0.f, 0.f};
            float nm[4]  = {0.f, 0.f, 0.f, 0.f};
            for (int v = 0; v < V; ++v) {
                float rv  = rho[p * V + v];
                float mk  = (mask[p * V + v] != 0.0f) ? 0.0f : -1e30f;
                float fw  = s_fT[w][v];
                float dr = rv - mu_r;
                float argr = fmaf(dr * dr, c_sr, mk);
                #pragma unroll
                for (int kk = 0; kk < 4; ++kk) {
                    float x = s_x[4 * j + kk][v];
                    float t = x - mu_t;
                    float e = __builtin_amdgcn_exp2f(fmaf(t * t, c_st, argr));
                    den[kk] += e;
                    nm[kk] = fmaf(e, fw, nm[kk]);
                }
            }
            #pragma unroll
            for (int kk = 0; kk < 4; ++kk)
                s_descT[(w * 16 + 4 * j + kk) * GPAD + g] =
                    (elem_t)__builtin_bit_cast(elem_t,
                        estore(nm[kk] * __builtin_amdgcn_rcpf(den[kk] + EPSV)));
        }
    }

    __syncthreads();                               // barrier #3 (descT ready)

    // ---- stage-3 MFMA: out = max_k descT x Wc + bc; Wc loaded per-nt ----
    {
        const int ww = tid >> 6;
        const int l  = tid & 63;
        const int lg = l >> 4, lc = l & 15;
        efrag afrag[3];
        #pragma unroll
        for (int ks = 0; ks < 3; ++ks)
            afrag[ks] = *(const efrag*)(s_descT + (ww * 16 + lc) * GPAD +
                                        ks * 32 + (lg << 3));
        // lane's Wc column base: row g stride O floats
        const float* wbase = Wc + (size_t)(ww * G) * O + lc;

        #pragma unroll 1
        for (int nt = 0; nt < 5; ++nt) {
            const float* wp = wbase + nt * 16;
            // load 3 B-frags (24 floats, bounded live range, no barrier cross)
            float v0[8], v1[8], v2[8];
            #pragma unroll
            for (int i = 0; i < 8; ++i) {
                int ga = (lg << 3) + i;            // ks=0: g 0..31
                int gb = 32 + (lg << 3) + i;       // ks=1: g 32..63
                int gc = 64 + (lg << 3) + i;       // ks=2: g 64..95 (pad>=80)
                v0[i] = wp[(size_t)ga * O];
                v1[i] = wp[(size_t)gb * O];
                v2[i] = (gc < G) ? wp[(size_t)gc * O] : 0.0f;
            }
            efrag b0 = __builtin_bit_cast(efrag, make_uint4(
                epack(v0[0], v0[1]), epack(v0[2], v0[3]),
                epack(v0[4], v0[5]), epack(v0[6], v0[7])));
            efrag b1 = __builtin_bit_cast(efrag, make_uint4(
                epack(v1[0], v1[1]), epack(v1[2], v1[3]),
                epack(v1[4], v1[5]), epack(v1[6], v1[7])));
            efrag b2 = __builtin_bit_cast(efrag, make_uint4(
                epack(v2[0], v2[1]), epack(v2[2], v2[3]),
                epack(v2[4], v2[5]), epack(v2[6], v2[7])));

            f32x4 acc = {0.f, 0.f, 0.f, 0.f};
            __builtin_amdgcn_s_setprio(1);
            acc = EMFMA(afrag[0], b0, acc);
            acc = EMFMA(afrag[1], b1, acc);
            acc = EMFMA(afrag[2], b2, acc);
            __builtin_amdgcn_s_setprio(0);
            float m1 = fmaxf(fmaxf(acc[0], acc[1]), fmaxf(acc[2], acc[3]));
            m1 = fmaxf(m1, __shfl_xor(m1, 16));
            m1 = fmaxf(m1, __shfl_xor(m1, 32));
            if (l < 16) {
                int oo = nt * 16 + l;
                out[p * (W * O) + ww * O + oo] = m1 + bc[ww * O + oo];
            }
        }
    }
}

extern "C" void kernel_launch(void* const* d_in, const int* in_sizes, int n_in,
                              void* d_out, int out_size, void* d_ws, size_t ws_size,
                              hipStream_t stream) {
    const float* feat      = (const float*)d_in[0];
    const float* rho       = (const float*)d_in[1];
    const float* theta     = (const float*)d_in[2];
    const float* mask      = (const float*)d_in[3];
    const float* mu_rho    = (const float*)d_in[4];
    const float* mu_theta  = (const float*)d_in[5];
    const float* sig_rho   = (const float*)d_in[6];
    const float* sig_theta = (const float*)d_in[7];
    const float* Wc        = (const float*)d_in[8];
    const float* bc        = (const float*)d_in[9];
    float* outp            = (float*)d_out;

    const int np = in_sizes[1] / V;   // B*N points
    conv_kernel<<<np, 320, 0, stream>>>(feat, rho, theta, mask, mu_rho, mu_theta,
                                        sig_rho, sig_theta, Wc, bc, outp);
}